// Round 8
// baseline (347.626 us; speedup 1.0000x reference)
//
#include <hip/hip_runtime.h>
#include <math.h>

#define S_LEN 1024
#define QKV_N 5120

typedef __attribute__((ext_vector_type(8))) __bf16 bf16x8;
typedef __attribute__((ext_vector_type(4))) float f32x4;

__device__ __forceinline__ unsigned short f2bf(float f) {
  unsigned int u = __float_as_uint(f);
  u += 0x7fff + ((u >> 16) & 1);
  return (unsigned short)(u >> 16);
}
__device__ __forceinline__ float bf2f(unsigned short u) {
  return __uint_as_float((unsigned int)u << 16);
}

__device__ __forceinline__ void async_copy16(const void* g, void* l) {
  __builtin_amdgcn_global_load_lds(
      (const __attribute__((address_space(1))) unsigned int*)g,
      (__attribute__((address_space(3))) unsigned int*)l, 16, 0, 0);
}

// convert 8 fp32 -> bf16x8 and store 16B to LDS (RTNE == f2bf on finite values)
__device__ __forceinline__ void cvt_store8(unsigned short* dst, float4 u0, float4 u1) {
  bf16x8 v;
  v[0] = (__bf16)u0.x; v[1] = (__bf16)u0.y; v[2] = (__bf16)u0.z; v[3] = (__bf16)u0.w;
  v[4] = (__bf16)u1.x; v[5] = (__bf16)u1.y; v[6] = (__bf16)u1.z; v[7] = (__bf16)u1.w;
  *(bf16x8*)dst = v;
}

// ---------------- tiny prep: bias concat + YaRN tables ----------------
__global__ void prep_small(const float* __restrict__ bq, const float* __restrict__ bk,
                           const float* __restrict__ bv, const int* __restrict__ positions,
                           float* __restrict__ bqkv, float* __restrict__ cosT,
                           float* __restrict__ sinT, float low, float high, float mscale) {
  int i = blockIdx.x * 256 + threadIdx.x;
  if (i < 1280) {
    int c0 = i * 4;
    float4 v;
    if (c0 < 4096)      v = ((const float4*)bq)[i];
    else if (c0 < 4608) v = ((const float4*)bk)[i - 1024];
    else                v = ((const float4*)bv)[i - 1152];
    ((float4*)bqkv)[i] = v;
  } else if (i < 9472) {
    int tid = i - 1280;            // 0..8191
    int s = tid >> 3;
    int j0 = (tid & 7) * 4;
    float pos = (float)positions[s];
    float4 cv, sv;
    float* cc = (float*)&cv;
    float* ss = (float*)&sv;
#pragma unroll
    for (int e = 0; e < 4; e++) {
      int j = j0 + e;
      float pf = powf(150000.0f, (float)j / 32.0f);
      float ramp = ((float)j - low) / (high - low);
      ramp = fminf(fmaxf(ramp, 0.0f), 1.0f);
      float invf = (1.0f / (32.0f * pf)) * ramp + (1.0f / pf) * (1.0f - ramp);
      float ang = pos * invf;
      cc[e] = cosf(ang) * mscale;
      ss[e] = sinf(ang) * mscale;
    }
    ((float4*)cosT)[s * 8 + (tid & 7)] = cv;
    ((float4*)sinT)[s * 8 + (tid & 7)] = sv;
  }
}

// ---------------- fused: (reduce+rope Q,K) | (reduce+transpose V) ----------------
__global__ __launch_bounds__(256) void rope_vtrans(
    const unsigned short* __restrict__ part, const float* __restrict__ bqkv,
    const float* __restrict__ cosT, const float* __restrict__ sinT,
    unsigned short* __restrict__ Qb, unsigned short* __restrict__ Kb,
    unsigned short* __restrict__ Vt, int SP) {
  const int bx = blockIdx.x;
  const int t = threadIdx.x;
  __shared__ unsigned short tile[128][66];
  if (bx < 9216) {
    int idx = bx * 256 + t;  // S*72*32
    int j = idx & 31;
    int hh = (idx >> 5) % 72;
    int s = idx / (72 * 32);
    int c1 = hh * 64 + j, c2 = c1 + 32;
    float xv = bqkv[c1], yv = bqkv[c2];
    for (int sp = 0; sp < SP; sp++) {
      const unsigned short* P = part + (size_t)sp * S_LEN * QKV_N + (size_t)s * QKV_N;
      xv += bf2f(P[c1]);
      yv += bf2f(P[c2]);
    }
    float c = cosT[s * 32 + j], sn = sinT[s * 32 + j];
    float o1 = xv * c - yv * sn;
    float o2 = yv * c + xv * sn;
    if (hh < 64) {
      unsigned short* q = Qb + ((size_t)s * 64 + hh) * 64;
      q[j]      = f2bf(o1 * 0.125f);   // fold in D^-0.5
      q[j + 32] = f2bf(o2 * 0.125f);
    } else {
      unsigned short* k = Kb + ((size_t)s * 8 + (hh - 64)) * 64;
      k[j]      = f2bf(o1);
      k[j + 32] = f2bf(o2);
    }
  } else {
    const int b = bx - 9216;
    const int kvh = b >> 3, s0 = (b & 7) * 128;
#pragma unroll
    for (int i = 0; i < 32; i++) {
      int e = t + i * 256;
      int s = e >> 6, d = e & 63;
      int col = 4608 + kvh * 64 + d;
      float v = bqkv[col];
      for (int sp = 0; sp < SP; sp++)
        v += bf2f(part[(size_t)sp * S_LEN * QKV_N + (size_t)(s0 + s) * QKV_N + col]);
      tile[s][d] = f2bf(v);
    }
    __syncthreads();
#pragma unroll
    for (int i = 0; i < 32; i++) {
      int e = t + i * 256;
      int d = e >> 7, s = e & 127;
      Vt[((size_t)kvh * 64 + d) * 1024 + s0 + s] = tile[s][d];
    }
  }
}

// ---------------- NT MFMA GEMM, BK=64, XOR-swizzled LDS, split-K, fused fp32->bf16 ----------------
// A: bf16 (async DMA) when A_BF16, else fp32 staged via VGPR-convert.
// B: always fp32 (weights direct from inputs), 3-segment row->pointer select.
// LDS layout unchanged: (row, kgroup) at slot row*64 + (kgroup^(row&7))*8.
template <bool A_BF16>
__global__ __launch_bounds__(256) void gemm_fused(
    const void* __restrict__ Av, const float* __restrict__ B0,
    const float* __restrict__ B1, const float* __restrict__ B2,
    int b1row, int b2row,
    unsigned short* __restrict__ part, int M, int N, int K, int NT, int SP) {
  __shared__ __align__(16) unsigned short As[128 * 64];
  __shared__ __align__(16) unsigned short Bs[128 * 64];
  const int lb = blockIdx.x;
  const int aI = lb >> 6;
  const int rem = lb & 63;
  const int mI = rem >> 3;
  const int bI = rem & 7;
  const int c = aI * 8 + bI;
  if (c >= NT * SP) return;
  const int sI = c / NT, nI = c % NT;
  const int m0 = mI * 128, n0 = nI * 128;

  const int t = threadIdx.x;
  const int l = t & 63;
  const int w = t >> 6;
  const int lr = l & 15, lq = l >> 4;
  const int wm = (w >> 1) * 64, wn = (w & 1) * 64;

  const int T = K >> 6;                 // 64-wide k-iters
  const int kb = ((sI * T) / SP) * 64;
  const int ke = (((sI + 1) * T) / SP) * 64;

  const unsigned short* gA[4];
  const float* gA32[4];
  const float* gB32[4];
  unsigned short* lA[4];
  unsigned short* lB[4];
#pragma unroll
  for (int q = 0; q < 4; q++) {
    int s = q * 256 + t;            // LDS slot 0..1023
    int row = s >> 3;               // 0..127
    int kg = (s & 7) ^ (row & 7);   // global k-group this lane fetches
    if (A_BF16)
      gA[q] = (const unsigned short*)Av + (size_t)(m0 + row) * K + kg * 8;
    else
      gA32[q] = (const float*)Av + (size_t)(m0 + row) * K + kg * 8;
    lA[q] = &As[s * 8];
    int rb = n0 + row; if (rb > N - 1) rb = N - 1;
    const float* bb = (rb < b1row) ? B0 + (size_t)rb * K
                     : (rb < b2row) ? B1 + (size_t)(rb - b1row) * K
                                    : B2 + (size_t)(rb - b2row) * K;
    gB32[q] = bb + kg * 8;
    lB[q] = &Bs[s * 8];
  }

  f32x4 acc[4][4] = {};

  for (int k0 = kb; k0 < ke; k0 += 64) {
    if (A_BF16) {
#pragma unroll
      for (int q = 0; q < 4; q++) async_copy16(gA[q] + k0, lA[q]);
    } else {
#pragma unroll
      for (int q = 0; q < 4; q++) {
        float4 u0 = *(const float4*)(gA32[q] + k0);
        float4 u1 = *(const float4*)(gA32[q] + k0 + 4);
        cvt_store8(lA[q], u0, u1);
      }
    }
#pragma unroll
    for (int q = 0; q < 4; q++) {
      float4 u0 = *(const float4*)(gB32[q] + k0);
      float4 u1 = *(const float4*)(gB32[q] + k0 + 4);
      cvt_store8(lB[q], u0, u1);
    }
    __syncthreads();
#pragma unroll
    for (int h = 0; h < 2; h++) {
      bf16x8 af[4], bf[4];
#pragma unroll
      for (int i = 0; i < 4; i++) {
        int row = wm + i * 16 + lr;
        af[i] = *(const bf16x8*)&As[row * 64 + (((h << 2) | lq) ^ (row & 7)) * 8];
      }
#pragma unroll
      for (int i = 0; i < 4; i++) {
        int row = wn + i * 16 + lr;
        bf[i] = *(const bf16x8*)&Bs[row * 64 + (((h << 2) | lq) ^ (row & 7)) * 8];
      }
#pragma unroll
      for (int mi = 0; mi < 4; mi++)
#pragma unroll
        for (int ni = 0; ni < 4; ni++)
          acc[mi][ni] = __builtin_amdgcn_mfma_f32_16x16x32_bf16(af[mi], bf[ni], acc[mi][ni], 0, 0, 0);
    }
    __syncthreads();
  }

  unsigned short* P = part + (size_t)sI * M * N;
#pragma unroll
  for (int mi = 0; mi < 4; mi++) {
#pragma unroll
    for (int ni = 0; ni < 4; ni++) {
      int col = n0 + wn + ni * 16 + lr;
      if (col < N) {
#pragma unroll
        for (int r = 0; r < 4; r++) {
          int row = m0 + wm + mi * 16 + lq * 4 + r;
          P[(size_t)row * N + col] = f2bf(acc[mi][ni][r]);
        }
      }
    }
  }
}

// ---------------- split-K reduce: sum bf16 partials + bias -> fp32 out ----------------
__global__ void reduce_f32(const unsigned short* __restrict__ part, const float* __restrict__ bias,
                           float* __restrict__ out, int SP) {
  int i = blockIdx.x * 256 + threadIdx.x;  // 0..368639 (8-elem chunks of 1024x2880)
  if (i >= 368640) return;
  float acc[8];
  int bc = (i % 360) * 8;
#pragma unroll
  for (int e = 0; e < 8; e++) acc[e] = bias[bc + e];
  for (int sp = 0; sp < SP; sp++) {
    const ushort4* P = (const ushort4*)(part + (size_t)sp * 2949120);
    ushort4 u0 = P[i * 2], u1 = P[i * 2 + 1];
    acc[0] += bf2f(u0.x); acc[1] += bf2f(u0.y); acc[2] += bf2f(u0.z); acc[3] += bf2f(u0.w);
    acc[4] += bf2f(u1.x); acc[5] += bf2f(u1.y); acc[6] += bf2f(u1.z); acc[7] += bf2f(u1.w);
  }
  float4 o0 = {acc[0], acc[1], acc[2], acc[3]};
  float4 o1 = {acc[4], acc[5], acc[6], acc[7]};
  ((float4*)out)[i * 2] = o0;
  ((float4*)out)[i * 2 + 1] = o1;
}

// ---------------- MFMA flash attention, sliding window + sinks ----------------
__global__ __launch_bounds__(64) void attn_mfma(
    const unsigned short* __restrict__ Qb,   // [S][H][64] bf16 (pre-scaled)
    const unsigned short* __restrict__ Kb,   // [S][KV][64] bf16
    const unsigned short* __restrict__ Vt,   // [KV*64][S] bf16 (+slack)
    const float* __restrict__ sinks,
    unsigned short* __restrict__ out) {      // [S][4096] bf16
  const int h = blockIdx.x;
  const int q0 = blockIdx.y * 16;
  const int kvh = h >> 3;
  const int l = threadIdx.x;
  const int n = l & 15;
  const int g = l >> 4;

  __shared__ __align__(16) unsigned short Pl[16][32];

  const unsigned short* qp = Qb + (((size_t)(q0 + n) * 64 + h) * 64 + g * 8);
  bf16x8 qf0 = *(const bf16x8*)qp;
  bf16x8 qf1 = *(const bf16x8*)(qp + 32);

  const int q_lane = q0 + n;
  int k_lo = q0 - 127; if (k_lo < 0) k_lo = 0;
  k_lo &= ~31;
  const int k_end = q0 + 16;

  float m = -3.0e38f, lsum = 0.0f;
  f32x4 oacc[4] = {};

  for (int kk = k_lo; kk < k_end; kk += 32) {
    int kr0 = kk + n;      if (kr0 > 1023) kr0 = 1023;
    int kr1 = kk + 16 + n; if (kr1 > 1023) kr1 = 1023;
    const unsigned short* kp0 = Kb + (((size_t)kr0 * 8 + kvh) * 64 + g * 8);
    const unsigned short* kp1 = Kb + (((size_t)kr1 * 8 + kvh) * 64 + g * 8);
    bf16x8 ka0 = *(const bf16x8*)kp0;
    bf16x8 ka1 = *(const bf16x8*)(kp0 + 32);
    bf16x8 kb0 = *(const bf16x8*)kp1;
    bf16x8 kb1 = *(const bf16x8*)(kp1 + 32);
    f32x4 st0 = {}, st1 = {};
    st0 = __builtin_amdgcn_mfma_f32_16x16x32_bf16(ka0, qf0, st0, 0, 0, 0);
    st0 = __builtin_amdgcn_mfma_f32_16x16x32_bf16(ka1, qf1, st0, 0, 0, 0);
    st1 = __builtin_amdgcn_mfma_f32_16x16x32_bf16(kb0, qf0, st1, 0, 0, 0);
    st1 = __builtin_amdgcn_mfma_f32_16x16x32_bf16(kb1, qf1, st1, 0, 0, 0);

    float tm = -3.0e38f;
#pragma unroll
    for (int r = 0; r < 4; r++) {
      int k0i = kk + 4 * g + r;
      int k1i = k0i + 16;
      bool ok0 = (k0i <= q_lane) && (q_lane - k0i < 128);
      bool ok1 = (k1i <= q_lane) && (q_lane - k1i < 128);
      st0[r] = ok0 ? st0[r] : -3.0e38f;
      st1[r] = ok1 ? st1[r] : -3.0e38f;
      tm = fmaxf(tm, fmaxf(st0[r], st1[r]));
    }
    tm = fmaxf(tm, __shfl_xor(tm, 16));
    tm = fmaxf(tm, __shfl_xor(tm, 32));

    float mn = fmaxf(m, tm);
    float corr = __expf(m - mn);
    m = mn;
    float p0[4], p1[4], ps = 0.0f;
#pragma unroll
    for (int r = 0; r < 4; r++) {
      p0[r] = __expf(st0[r] - mn);
      p1[r] = __expf(st1[r] - mn);
      ps += p0[r] + p1[r];
    }
    ps += __shfl_xor(ps, 16);
    ps += __shfl_xor(ps, 32);
    lsum = lsum * corr + ps;

    ushort4 w0, w1;
    w0.x = f2bf(p0[0]); w0.y = f2bf(p0[1]); w0.z = f2bf(p0[2]); w0.w = f2bf(p0[3]);
    w1.x = f2bf(p1[0]); w1.y = f2bf(p1[1]); w1.z = f2bf(p1[2]); w1.w = f2bf(p1[3]);
    *(ushort4*)&Pl[n][4 * g]      = w0;
    *(ushort4*)&Pl[n][16 + 4 * g] = w1;
    __syncthreads();
    bf16x8 pf = *(const bf16x8*)&Pl[n][8 * g];
    __syncthreads();

#pragma unroll
    for (int db = 0; db < 4; db++) {
      const unsigned short* vp = Vt + ((size_t)(kvh * 64 + db * 16 + n)) * 1024 + kk + 8 * g;
      bf16x8 vf = *(const bf16x8*)vp;
#pragma unroll
      for (int r = 0; r < 4; r++) oacc[db][r] *= corr;
      oacc[db] = __builtin_amdgcn_mfma_f32_16x16x32_bf16(vf, pf, oacc[db], 0, 0, 0);
    }
  }

  float sink = sinks[h];
  float mn2 = fmaxf(m, sink);
  float corr2 = __expf(m - mn2);
  float denom = lsum * corr2 + __expf(sink - mn2);
  float fs = corr2 / denom;

#pragma unroll
  for (int db = 0; db < 4; db++) {
    ushort4 r;
    r.x = f2bf(oacc[db][0] * fs);
    r.y = f2bf(oacc[db][1] * fs);
    r.z = f2bf(oacc[db][2] * fs);
    r.w = f2bf(oacc[db][3] * fs);
    *(ushort4*)(out + (size_t)q_lane * 4096 + h * 64 + db * 16 + 4 * g) = r;
  }
}

extern "C" void kernel_launch(void* const* d_in, const int* in_sizes, int n_in,
                              void* d_out, int out_size, void* d_ws, size_t ws_size,
                              hipStream_t stream) {
  const float* x = (const float*)d_in[0];
  const int* positions = (const int*)d_in[1];
  const float* Wq = (const float*)d_in[2];
  const float* bq = (const float*)d_in[3];
  const float* Wk = (const float*)d_in[4];
  const float* bk = (const float*)d_in[5];
  const float* Wv = (const float*)d_in[6];
  const float* bv = (const float*)d_in[7];
  const float* Wo = (const float*)d_in[8];
  const float* bo = (const float*)d_in[9];
  const float* sinks = (const float*)d_in[10];
  float* out = (float*)d_out;

  char* ws = (char*)d_ws;
  float* bqkv = (float*)(ws + 0);                  // 5120 f32
  float* cosT = (float*)(ws + 20480);              // 1024x32 f32
  float* sinT = (float*)(ws + 151552);             // 1024x32 f32
  const size_t SH = 282624;                        // shared region
  unsigned short* qkv_part = (unsigned short*)(ws + SH);           // split_q x 10,485,760 B
  unsigned short* out_part = (unsigned short*)(ws + SH);           // split_o x 5,898,240 B
  unsigned short* attnb    = (unsigned short*)(ws + SH + 23592960); // 8,388,608
  const size_t TL = SH + 41943040;
  unsigned short* Qb = (unsigned short*)(ws + TL);                 // 8,388,608
  unsigned short* Kb = (unsigned short*)(ws + TL + 8388608);       // 1,048,576
  unsigned short* Vt = (unsigned short*)(ws + TL + 9437184);       // 1,048,576 + slack

  int split_q = 4, split_o = 4;
  if (ws_size < TL + 10489984) {
    split_q = 2; split_o = 2;
    attnb = (unsigned short*)(ws + SH + 11796480);
    Qb = (unsigned short*)(ws + SH + 20971520);
    Kb = Qb + 4194304;
    Vt = Kb + 524288;
  }

  const double TWO_PI = 6.283185307179586;
  double lowd = 64.0 * log(4096.0 / (32.0 * TWO_PI)) / (2.0 * log(150000.0));
  if (lowd < 0.0) lowd = 0.0;
  double highd = 64.0 * log(4096.0 / (1.0 * TWO_PI)) / (2.0 * log(150000.0));
  if (highd > 31.0) highd = 31.0;
  if (lowd == highd) highd += 0.001;
  float mscale = (float)(0.1 * log(32.0) + 1.0);

  // 1. bias concat + rope tables (tiny)
  prep_small<<<37, 256, 0, stream>>>(bq, bk, bv, positions, bqkv, cosT, sinT,
                                     (float)lowd, (float)highd, mscale);

  // 2. QKV projection: A=x fp32, B=[Wq;Wk;Wv] fp32, fused convert in staging
  {
    int NT = 40, C = NT * split_q;
    int grid = 64 * ((C + 7) / 8);
    gemm_fused<false><<<grid, 256, 0, stream>>>(x, Wq, Wk, Wv, 4096, 4608,
                                                qkv_part, 1024, 5120, 2880, NT, split_q);
  }

  // 3. fused reduce+rope (Q,K) and reduce+transpose (V)
  rope_vtrans<<<9280, 256, 0, stream>>>(qkv_part, bqkv, cosT, sinT, Qb, Kb, Vt, split_q);

  // 4. attention
  attn_mfma<<<dim3(64, 64), 64, 0, stream>>>(Qb, Kb, Vt, sinks, attnb);

  // 5. output projection: A=attnb bf16 (DMA), B=Wo fp32 fused convert
  {
    int NT = 23, C = NT * split_o;
    int grid = 64 * ((C + 7) / 8);
    gemm_fused<true><<<grid, 256, 0, stream>>>(attnb, Wo, Wo, Wo, 1 << 30, 1 << 30,
                                               out_part, 1024, 2880, 4096, NT, split_o);
  }

  // 6. final reduce + bias -> fp32
  reduce_f32<<<1440, 256, 0, stream>>>(out_part, bo, out, split_o);
}

// Round 10
// 306.957 us; speedup vs baseline: 1.1325x; 1.1325x over previous
//
#include <hip/hip_runtime.h>
#include <math.h>

#define S_LEN 1024
#define QKV_N 5120

typedef __attribute__((ext_vector_type(8))) __bf16 bf16x8;
typedef __attribute__((ext_vector_type(4))) float f32x4;

__device__ __forceinline__ unsigned short f2bf(float f) {
  unsigned int u = __float_as_uint(f);
  u += 0x7fff + ((u >> 16) & 1);
  return (unsigned short)(u >> 16);
}
__device__ __forceinline__ float bf2f(unsigned short u) {
  return __uint_as_float((unsigned int)u << 16);
}

__device__ __forceinline__ void async_copy16(const void* g, void* l) {
  __builtin_amdgcn_global_load_lds(
      (const __attribute__((address_space(1))) unsigned int*)g,
      (__attribute__((address_space(3))) unsigned int*)l, 16, 0, 0);
}

__device__ __forceinline__ ushort4 cvt4(float4 v) {
  ushort4 r;
  r.x = f2bf(v.x); r.y = f2bf(v.y); r.z = f2bf(v.z); r.w = f2bf(v.w);
  return r;
}

// ---------------- mega-fused prep: converts (4 f4/thread, forced MLP) + bias + tables ----
// blocks [0,7200): base = blk*1024, each block covers 1024 f4 items via
// loads at off, off+256, off+512, off+768 (CORRECTED round-8 bug: base was blk*4096
// leaving 3/4 of the buffers poisoned). All segment boundaries are multiples of
// 1024 so the segment select is wave-uniform. sched_barrier(0) between the load
// group and store group forbids min-register load/store pairing (round-6/7: VGPR=24
// proved serialization) -> 4 loads in flight per thread.
// blocks [7200,7237): bias concat (1280 items) + YaRN tables (8192 items).
__global__ void prep_all(const float* __restrict__ x, const float* __restrict__ Wq,
                         const float* __restrict__ Wk, const float* __restrict__ Wv,
                         const float* __restrict__ Wo, const float* __restrict__ bq,
                         const float* __restrict__ bk, const float* __restrict__ bv,
                         const int* __restrict__ positions,
                         unsigned short* __restrict__ xb, unsigned short* __restrict__ wqkv,
                         unsigned short* __restrict__ wo, float* __restrict__ bqkv,
                         float* __restrict__ cosT, float* __restrict__ sinT,
                         float low, float high, float mscale) {
  const int blk = blockIdx.x;
  const int t = threadIdx.x;
  if (blk < 7200) {
    const int base = blk << 10;
    const float* src;
    unsigned short* dst;
    int segbase;
    if (base < 737280)       { src = x;  dst = xb;                          segbase = 0; }
    else if (base < 3686400) { src = Wq; dst = wqkv;                        segbase = 737280; }
    else if (base < 4055040) { src = Wk; dst = wqkv + (size_t)4096 * 2880;  segbase = 3686400; }
    else if (base < 4423680) { src = Wv; dst = wqkv + (size_t)4608 * 2880;  segbase = 4055040; }
    else                     { src = Wo; dst = wo;                          segbase = 4423680; }
    const int off = base - segbase + t;
    const float4* s4 = (const float4*)src + off;
    ushort4* d4 = (ushort4*)dst + off;
    float4 v0 = s4[0];
    float4 v1 = s4[256];
    float4 v2 = s4[512];
    float4 v3 = s4[768];
    __builtin_amdgcn_sched_barrier(0);  // all 4 loads issued before any store
    d4[0]   = cvt4(v0);
    d4[256] = cvt4(v1);
    d4[512] = cvt4(v2);
    d4[768] = cvt4(v3);
  } else {
    int i = (blk - 7200) * 256 + t;  // 0..9471
    if (i < 1280) {
      int c0 = i * 4;
      float4 v;
      if (c0 < 4096)      v = ((const float4*)bq)[i];
      else if (c0 < 4608) v = ((const float4*)bk)[i - 1024];
      else                v = ((const float4*)bv)[i - 1152];
      ((float4*)bqkv)[i] = v;
    } else if (i < 9472) {
      int tid = i - 1280;            // 0..8191
      int s = tid >> 3;
      int j0 = (tid & 7) * 4;
      float pos = (float)positions[s];
      float4 cv, sv;
      float* cc = (float*)&cv;
      float* ss = (float*)&sv;
#pragma unroll
      for (int e = 0; e < 4; e++) {
        int j = j0 + e;
        float pf = powf(150000.0f, (float)j / 32.0f);
        float ramp = ((float)j - low) / (high - low);
        ramp = fminf(fmaxf(ramp, 0.0f), 1.0f);
        float invf = (1.0f / (32.0f * pf)) * ramp + (1.0f / pf) * (1.0f - ramp);
        float ang = pos * invf;
        cc[e] = cosf(ang) * mscale;
        ss[e] = sinf(ang) * mscale;
      }
      ((float4*)cosT)[s * 8 + (tid & 7)] = cv;
      ((float4*)sinT)[s * 8 + (tid & 7)] = sv;
    }
  }
}

// ---------------- fused: (reduce+rope Q,K) | (reduce+transpose V) ----------------
__global__ __launch_bounds__(256) void rope_vtrans(
    const unsigned short* __restrict__ part, const float* __restrict__ bqkv,
    const float* __restrict__ cosT, const float* __restrict__ sinT,
    unsigned short* __restrict__ Qb, unsigned short* __restrict__ Kb,
    unsigned short* __restrict__ Vt, int SP) {
  const int bx = blockIdx.x;
  const int t = threadIdx.x;
  __shared__ unsigned short tile[128][66];
  if (bx < 9216) {
    int idx = bx * 256 + t;  // S*72*32
    int j = idx & 31;
    int hh = (idx >> 5) % 72;
    int s = idx / (72 * 32);
    int c1 = hh * 64 + j, c2 = c1 + 32;
    float xv = bqkv[c1], yv = bqkv[c2];
    for (int sp = 0; sp < SP; sp++) {
      const unsigned short* P = part + (size_t)sp * S_LEN * QKV_N + (size_t)s * QKV_N;
      xv += bf2f(P[c1]);
      yv += bf2f(P[c2]);
    }
    float c = cosT[s * 32 + j], sn = sinT[s * 32 + j];
    float o1 = xv * c - yv * sn;
    float o2 = yv * c + xv * sn;
    if (hh < 64) {
      unsigned short* q = Qb + ((size_t)s * 64 + hh) * 64;
      q[j]      = f2bf(o1 * 0.125f);   // fold in D^-0.5
      q[j + 32] = f2bf(o2 * 0.125f);
    } else {
      unsigned short* k = Kb + ((size_t)s * 8 + (hh - 64)) * 64;
      k[j]      = f2bf(o1);
      k[j + 32] = f2bf(o2);
    }
  } else {
    const int b = bx - 9216;
    const int kvh = b >> 3, s0 = (b & 7) * 128;
#pragma unroll
    for (int i = 0; i < 32; i++) {
      int e = t + i * 256;
      int s = e >> 6, d = e & 63;
      int col = 4608 + kvh * 64 + d;
      float v = bqkv[col];
      for (int sp = 0; sp < SP; sp++)
        v += bf2f(part[(size_t)sp * S_LEN * QKV_N + (size_t)(s0 + s) * QKV_N + col]);
      tile[s][d] = f2bf(v);
    }
    __syncthreads();
#pragma unroll
    for (int i = 0; i < 32; i++) {
      int e = t + i * 256;
      int d = e >> 7, s = e & 127;
      Vt[((size_t)kvh * 64 + d) * 1024 + s0 + s] = tile[s][d];
    }
  }
}

// ---------------- NT bf16 MFMA GEMM, BK=64, XOR-bank-swizzled LDS, split-K ----------------
__global__ __launch_bounds__(256) void gemm_bt_sk(
    const unsigned short* __restrict__ A, const unsigned short* __restrict__ B,
    unsigned short* __restrict__ part, int M, int N, int K, int NT, int SP) {
  __shared__ __align__(16) unsigned short As[128 * 64];
  __shared__ __align__(16) unsigned short Bs[128 * 64];
  const int lb = blockIdx.x;
  const int aI = lb >> 6;
  const int rem = lb & 63;
  const int mI = rem >> 3;
  const int bI = rem & 7;
  const int c = aI * 8 + bI;
  if (c >= NT * SP) return;
  const int sI = c / NT, nI = c % NT;
  const int m0 = mI * 128, n0 = nI * 128;

  const int t = threadIdx.x;
  const int l = t & 63;
  const int w = t >> 6;
  const int lr = l & 15, lq = l >> 4;
  const int wm = (w >> 1) * 64, wn = (w & 1) * 64;

  const int T = K >> 6;                 // 64-wide k-iters
  const int kb = ((sI * T) / SP) * 64;
  const int ke = (((sI + 1) * T) / SP) * 64;

  const unsigned short* gA[4];
  const unsigned short* gB[4];
  unsigned short* lA[4];
  unsigned short* lB[4];
#pragma unroll
  for (int q = 0; q < 4; q++) {
    int s = q * 256 + t;            // LDS slot 0..1023
    int row = s >> 3;               // 0..127
    int kg = (s & 7) ^ (row & 7);   // global k-group this lane fetches
    gA[q] = A + (size_t)(m0 + row) * K + kg * 8;
    int rb = n0 + row; if (rb > N - 1) rb = N - 1;
    gB[q] = B + (size_t)rb * K + kg * 8;
    lA[q] = &As[s * 8];
    lB[q] = &Bs[s * 8];
  }

  f32x4 acc[4][4] = {};

  for (int k0 = kb; k0 < ke; k0 += 64) {
#pragma unroll
    for (int q = 0; q < 4; q++) async_copy16(gA[q] + k0, lA[q]);
#pragma unroll
    for (int q = 0; q < 4; q++) async_copy16(gB[q] + k0, lB[q]);
    __syncthreads();
#pragma unroll
    for (int h = 0; h < 2; h++) {
      bf16x8 af[4], bf[4];
#pragma unroll
      for (int i = 0; i < 4; i++) {
        int row = wm + i * 16 + lr;
        af[i] = *(const bf16x8*)&As[row * 64 + (((h << 2) | lq) ^ (row & 7)) * 8];
      }
#pragma unroll
      for (int i = 0; i < 4; i++) {
        int row = wn + i * 16 + lr;
        bf[i] = *(const bf16x8*)&Bs[row * 64 + (((h << 2) | lq) ^ (row & 7)) * 8];
      }
#pragma unroll
      for (int mi = 0; mi < 4; mi++)
#pragma unroll
        for (int ni = 0; ni < 4; ni++)
          acc[mi][ni] = __builtin_amdgcn_mfma_f32_16x16x32_bf16(af[mi], bf[ni], acc[mi][ni], 0, 0, 0);
    }
    __syncthreads();
  }

  unsigned short* P = part + (size_t)sI * M * N;
#pragma unroll
  for (int mi = 0; mi < 4; mi++) {
#pragma unroll
    for (int ni = 0; ni < 4; ni++) {
      int col = n0 + wn + ni * 16 + lr;
      if (col < N) {
#pragma unroll
        for (int r = 0; r < 4; r++) {
          int row = m0 + wm + mi * 16 + lq * 4 + r;
          P[(size_t)row * N + col] = f2bf(acc[mi][ni][r]);
        }
      }
    }
  }
}

// ---------------- split-K reduce: sum bf16 partials + bias -> fp32 out ----------------
__global__ void reduce_f32(const unsigned short* __restrict__ part, const float* __restrict__ bias,
                           float* __restrict__ out, int SP) {
  int i = blockIdx.x * 256 + threadIdx.x;  // 0..368639 (8-elem chunks of 1024x2880)
  if (i >= 368640) return;
  float acc[8];
  int bc = (i % 360) * 8;
#pragma unroll
  for (int e = 0; e < 8; e++) acc[e] = bias[bc + e];
  for (int sp = 0; sp < SP; sp++) {
    const ushort4* P = (const ushort4*)(part + (size_t)sp * 2949120);
    ushort4 u0 = P[i * 2], u1 = P[i * 2 + 1];
    acc[0] += bf2f(u0.x); acc[1] += bf2f(u0.y); acc[2] += bf2f(u0.z); acc[3] += bf2f(u0.w);
    acc[4] += bf2f(u1.x); acc[5] += bf2f(u1.y); acc[6] += bf2f(u1.z); acc[7] += bf2f(u1.w);
  }
  float4 o0 = {acc[0], acc[1], acc[2], acc[3]};
  float4 o1 = {acc[4], acc[5], acc[6], acc[7]};
  ((float4*)out)[i * 2] = o0;
  ((float4*)out)[i * 2 + 1] = o1;
}

// ---------------- MFMA flash attention, sliding window + sinks ----------------
__global__ __launch_bounds__(64) void attn_mfma(
    const unsigned short* __restrict__ Qb,   // [S][H][64] bf16 (pre-scaled)
    const unsigned short* __restrict__ Kb,   // [S][KV][64] bf16
    const unsigned short* __restrict__ Vt,   // [KV*64][S] bf16 (+slack)
    const float* __restrict__ sinks,
    unsigned short* __restrict__ out) {      // [S][4096] bf16
  const int h = blockIdx.x;
  const int q0 = blockIdx.y * 16;
  const int kvh = h >> 3;
  const int l = threadIdx.x;
  const int n = l & 15;
  const int g = l >> 4;

  __shared__ __align__(16) unsigned short Pl[16][32];

  const unsigned short* qp = Qb + (((size_t)(q0 + n) * 64 + h) * 64 + g * 8);
  bf16x8 qf0 = *(const bf16x8*)qp;
  bf16x8 qf1 = *(const bf16x8*)(qp + 32);

  const int q_lane = q0 + n;
  int k_lo = q0 - 127; if (k_lo < 0) k_lo = 0;
  k_lo &= ~31;
  const int k_end = q0 + 16;

  float m = -3.0e38f, lsum = 0.0f;
  f32x4 oacc[4] = {};

  for (int kk = k_lo; kk < k_end; kk += 32) {
    int kr0 = kk + n;      if (kr0 > 1023) kr0 = 1023;
    int kr1 = kk + 16 + n; if (kr1 > 1023) kr1 = 1023;
    const unsigned short* kp0 = Kb + (((size_t)kr0 * 8 + kvh) * 64 + g * 8);
    const unsigned short* kp1 = Kb + (((size_t)kr1 * 8 + kvh) * 64 + g * 8);
    bf16x8 ka0 = *(const bf16x8*)kp0;
    bf16x8 ka1 = *(const bf16x8*)(kp0 + 32);
    bf16x8 kb0 = *(const bf16x8*)kp1;
    bf16x8 kb1 = *(const bf16x8*)(kp1 + 32);
    f32x4 st0 = {}, st1 = {};
    st0 = __builtin_amdgcn_mfma_f32_16x16x32_bf16(ka0, qf0, st0, 0, 0, 0);
    st0 = __builtin_amdgcn_mfma_f32_16x16x32_bf16(ka1, qf1, st0, 0, 0, 0);
    st1 = __builtin_amdgcn_mfma_f32_16x16x32_bf16(kb0, qf0, st1, 0, 0, 0);
    st1 = __builtin_amdgcn_mfma_f32_16x16x32_bf16(kb1, qf1, st1, 0, 0, 0);

    float tm = -3.0e38f;
#pragma unroll
    for (int r = 0; r < 4; r++) {
      int k0i = kk + 4 * g + r;
      int k1i = k0i + 16;
      bool ok0 = (k0i <= q_lane) && (q_lane - k0i < 128);
      bool ok1 = (k1i <= q_lane) && (q_lane - k1i < 128);
      st0[r] = ok0 ? st0[r] : -3.0e38f;
      st1[r] = ok1 ? st1[r] : -3.0e38f;
      tm = fmaxf(tm, fmaxf(st0[r], st1[r]));
    }
    tm = fmaxf(tm, __shfl_xor(tm, 16));
    tm = fmaxf(tm, __shfl_xor(tm, 32));

    float mn = fmaxf(m, tm);
    float corr = __expf(m - mn);
    m = mn;
    float p0[4], p1[4], ps = 0.0f;
#pragma unroll
    for (int r = 0; r < 4; r++) {
      p0[r] = __expf(st0[r] - mn);
      p1[r] = __expf(st1[r] - mn);
      ps += p0[r] + p1[r];
    }
    ps += __shfl_xor(ps, 16);
    ps += __shfl_xor(ps, 32);
    lsum = lsum * corr + ps;

    ushort4 w0, w1;
    w0.x = f2bf(p0[0]); w0.y = f2bf(p0[1]); w0.z = f2bf(p0[2]); w0.w = f2bf(p0[3]);
    w1.x = f2bf(p1[0]); w1.y = f2bf(p1[1]); w1.z = f2bf(p1[2]); w1.w = f2bf(p1[3]);
    *(ushort4*)&Pl[n][4 * g]      = w0;
    *(ushort4*)&Pl[n][16 + 4 * g] = w1;
    __syncthreads();
    bf16x8 pf = *(const bf16x8*)&Pl[n][8 * g];
    __syncthreads();

#pragma unroll
    for (int db = 0; db < 4; db++) {
      const unsigned short* vp = Vt + ((size_t)(kvh * 64 + db * 16 + n)) * 1024 + kk + 8 * g;
      bf16x8 vf = *(const bf16x8*)vp;
#pragma unroll
      for (int r = 0; r < 4; r++) oacc[db][r] *= corr;
      oacc[db] = __builtin_amdgcn_mfma_f32_16x16x32_bf16(vf, pf, oacc[db], 0, 0, 0);
    }
  }

  float sink = sinks[h];
  float mn2 = fmaxf(m, sink);
  float corr2 = __expf(m - mn2);
  float denom = lsum * corr2 + __expf(sink - mn2);
  float fs = corr2 / denom;

#pragma unroll
  for (int db = 0; db < 4; db++) {
    ushort4 r;
    r.x = f2bf(oacc[db][0] * fs);
    r.y = f2bf(oacc[db][1] * fs);
    r.z = f2bf(oacc[db][2] * fs);
    r.w = f2bf(oacc[db][3] * fs);
    *(ushort4*)(out + (size_t)q_lane * 4096 + h * 64 + db * 16 + 4 * g) = r;
  }
}

extern "C" void kernel_launch(void* const* d_in, const int* in_sizes, int n_in,
                              void* d_out, int out_size, void* d_ws, size_t ws_size,
                              hipStream_t stream) {
  const float* x = (const float*)d_in[0];
  const int* positions = (const int*)d_in[1];
  const float* Wq = (const float*)d_in[2];
  const float* bq = (const float*)d_in[3];
  const float* Wk = (const float*)d_in[4];
  const float* bk = (const float*)d_in[5];
  const float* Wv = (const float*)d_in[6];
  const float* bv = (const float*)d_in[7];
  const float* Wo = (const float*)d_in[8];
  const float* bo = (const float*)d_in[9];
  const float* sinks = (const float*)d_in[10];
  float* out = (float*)d_out;

  char* ws = (char*)d_ws;
  unsigned short* xb   = (unsigned short*)(ws + 0);          // 1024x2880 bf16
  unsigned short* wqkv = (unsigned short*)(ws + 5898240);    // 5120x2880 bf16
  unsigned short* wo   = (unsigned short*)(ws + 35389440);   // 2880x4096 bf16
  float* bqkv          = (float*)(ws + 58982400);            // 5120 f32
  float* cosT          = (float*)(ws + 59002880);            // 1024x32 f32
  float* sinT          = (float*)(ws + 59133952);            // 1024x32 f32
  const size_t SH = 59265024;                                // shared region
  unsigned short* qkv_part = (unsigned short*)(ws + SH);
  unsigned short* out_part = (unsigned short*)(ws + SH);            // split_o x 5,898,240
  unsigned short* attnb    = (unsigned short*)(ws + SH + 23592960); // 8,388,608
  const size_t TL = SH + 41943040;
  unsigned short* Qb = (unsigned short*)(ws + TL);                  // 8,388,608
  unsigned short* Kb = (unsigned short*)(ws + TL + 8388608);        // 1,048,576
  unsigned short* Vt = (unsigned short*)(ws + TL + 9437184);        // 1,048,576 + slack

  int split_q = 4, split_o = 4;
  if (ws_size < TL + 10485888) {
    split_q = 2; split_o = 2;
    attnb = (unsigned short*)(ws + SH + 11796480);
    Qb = (unsigned short*)(ws + SH + 20971520);
    Kb = Qb + 4194304;
    Vt = Kb + 524288;
  }

  const double TWO_PI = 6.283185307179586;
  double lowd = 64.0 * log(4096.0 / (32.0 * TWO_PI)) / (2.0 * log(150000.0));
  if (lowd < 0.0) lowd = 0.0;
  double highd = 64.0 * log(4096.0 / (1.0 * TWO_PI)) / (2.0 * log(150000.0));
  if (highd > 31.0) highd = 31.0;
  if (lowd == highd) highd += 0.001;
  float mscale = (float)(0.1 * log(32.0) + 1.0);

  // 1. all converts (corrected forced-MLP 4 f4/thread) + bias + rope tables
  prep_all<<<7237, 256, 0, stream>>>(x, Wq, Wk, Wv, Wo, bq, bk, bv, positions,
                                     xb, wqkv, wo, bqkv, cosT, sinT,
                                     (float)lowd, (float)highd, mscale);

  // 2. QKV projection: split-K bf16 partials (XCD-swizzled grid, BK=64)
  {
    int NT = 40, C = NT * split_q;
    int grid = 64 * ((C + 7) / 8);
    gemm_bt_sk<<<grid, 256, 0, stream>>>(xb, wqkv, qkv_part, 1024, 5120, 2880, NT, split_q);
  }

  // 3. fused reduce+rope (Q,K) and reduce+transpose (V)
  rope_vtrans<<<9280, 256, 0, stream>>>(qkv_part, bqkv, cosT, sinT, Qb, Kb, Vt, split_q);

  // 4. attention
  attn_mfma<<<dim3(64, 64), 64, 0, stream>>>(Qb, Kb, Vt, sinks, attnb);

  // 5. output projection: split-K bf16 partials (BK=64)
  {
    int NT = 23, C = NT * split_o;
    int grid = 64 * ((C + 7) / 8);
    gemm_bt_sk<<<grid, 256, 0, stream>>>(attnb, wo, out_part, 1024, 2880, 4096, NT, split_o);
  }

  // 6. final reduce + bias -> fp32
  reduce_f32<<<1440, 256, 0, stream>>>(out_part, bo, out, split_o);
}